// Round 9
// baseline (134.052 us; speedup 1.0000x reference)
//
#include <hip/hip_runtime.h>

#define BATCH 8
#define NCH 11
#define HH 512
#define WW 512
#define HWSZ (HH*WW)
#define TILE 32
#define REG 40   // TILE + 8 halo
#define WBLEND 0.645f

// ---- monotone float<->uint encoding for atomic min/max (f32) ----
__device__ __forceinline__ unsigned encf(float f) {
    unsigned u = __float_as_uint(f);
    return u ^ ((unsigned)((int)u >> 31) | 0x80000000u);
}
__device__ __forceinline__ float decf(unsigned e) {
    unsigned u = (e & 0x80000000u) ? (e ^ 0x80000000u) : ~e;
    return __uint_as_float(u);
}

// ws: mm = [BATCH][NCH][2] u32 (704 B) @0; tileflag = [BATCH][16][16] u8 (2048 B) @704
__global__ void k_init(unsigned* __restrict__ mm, unsigned long long* __restrict__ fl) {
    int i = threadIdx.x;
    if (i < BATCH * NCH) { mm[2*i] = 0xFFFFFFFFu; mm[2*i+1] = 0u; }
    fl[i] = 0ULL;   // 256 * 8 = 2048 B of flags
}

// per-(b,pair) f32 min/max of the 10 channel diffs — float4, full occupancy
__global__ __launch_bounds__(256) void k_minmax(const float4* __restrict__ x4,
                                                unsigned* __restrict__ mm) {
    int b = blockIdx.y;
    const float4* xb = x4 + (size_t)b * 5 * (HWSZ/4);
    float mn[10], mx[10];
#pragma unroll
    for (int i = 0; i < 10; i++) { mn[i] = INFINITY; mx[i] = -INFINITY; }

    int p = blockIdx.x * blockDim.x + threadIdx.x;   // exactly HWSZ/4 threads
    float4 v0 = xb[p];
    float4 v1 = xb[(HWSZ/4) + p];
    float4 v2 = xb[2*(HWSZ/4) + p];
    float4 v3 = xb[3*(HWSZ/4) + p];
    float4 v4 = xb[4*(HWSZ/4) + p];
    const float* a0 = &v0.x; const float* a1 = &v1.x; const float* a2 = &v2.x;
    const float* a3 = &v3.x; const float* a4 = &v4.x;
#pragma unroll
    for (int c = 0; c < 4; c++) {
        float x0 = a0[c], x1 = a1[c], x2 = a2[c], x3 = a3[c], x4v = a4[c];
        float d[10] = { x0-x1, x0-x2, x0-x3, x0-x4v, x1-x2, x1-x3, x1-x4v, x2-x3, x2-x4v, x3-x4v };
#pragma unroll
        for (int i = 0; i < 10; i++) { mn[i] = fminf(mn[i], d[i]); mx[i] = fmaxf(mx[i], d[i]); }
    }
#pragma unroll
    for (int i = 0; i < 10; i++) {
#pragma unroll
        for (int off = 32; off; off >>= 1) {
            mn[i] = fminf(mn[i], __shfl_xor(mn[i], off));
            mx[i] = fmaxf(mx[i], __shfl_xor(mx[i], off));
        }
    }
    __shared__ float smn[4][10], smx[4][10];
    int w = threadIdx.x >> 6;
    if ((threadIdx.x & 63) == 0) {
#pragma unroll
        for (int i = 0; i < 10; i++) { smn[w][i] = mn[i]; smx[w][i] = mx[i]; }
    }
    __syncthreads();
    int t = threadIdx.x;
    if (t < 10) {
        float m = fminf(fminf(smn[0][t], smn[1][t]), fminf(smn[2][t], smn[3][t]));
        atomicMin(&mm[(b*NCH + t)*2], encf(m));
    } else if (t < 20) {
        int i = t - 10;
        float M = fmaxf(fmaxf(smx[0][i], smx[1][i]), fmaxf(smx[2][i], smx[3][i]));
        atomicMax(&mm[(b*NCH + i)*2 + 1], encf(M));
    }
}

// Two candidate bin maps (f32 chain / f64 chain) + per-tile diff flags.
// A diff pixel marks every tile whose 40x40 halo region contains it.
__global__ __launch_bounds__(256) void k_binidx(const float4* __restrict__ x4,
                                                const unsigned* __restrict__ mm,
                                                uchar4* __restrict__ bidx1,
                                                uchar4* __restrict__ bidx2,
                                                unsigned char* __restrict__ tileflag) {
    int b = blockIdx.y;
    float mnf = decf(mm[(b*NCH + 8)*2]);
    float mxf = decf(mm[(b*NCH + 8)*2 + 1]);
    float denf = mxf - mnf + 1e-6f;
    double mnd = (double)mnf;
    double dend = (double)mxf - (double)mnf + 1e-6;
    const float4* xb = x4 + (size_t)b * 5 * (HWSZ/4);
    uchar4* ib1 = bidx1 + (size_t)b * (HWSZ/4);
    uchar4* ib2 = bidx2 + (size_t)b * (HWSZ/4);
    int p = blockIdx.x * blockDim.x + threadIdx.x;    // exact grid
    float4 v2 = xb[2*(HWSZ/4) + p];
    float4 v4 = xb[4*(HWSZ/4) + p];
    const float* c2 = &v2.x; const float* c4 = &v4.x;
    unsigned char q1c[4], q2c[4];
#pragma unroll
    for (int c = 0; c < 4; c++) {
        float d = c2[c] - c4[c];
        float v1f = (d - mnf) / denf;
        q1c[c] = (unsigned char)(int)(v1f * 31.0f);
        double v2d = ((double)d - mnd) / dend;
        q2c[c] = (unsigned char)(int)(v2d * 31.0);
    }
    ib1[p] = make_uchar4(q1c[0], q1c[1], q1c[2], q1c[3]);
    ib2[p] = make_uchar4(q2c[0], q2c[1], q2c[2], q2c[3]);
#pragma unroll
    for (int c = 0; c < 4; c++) {
        if (q1c[c] != q2c[c]) {                      // rare
            int pix = p*4 + c;
            int gy = pix >> 9, gx = pix & (WW-1);
            int tylo = max(0, (gy-4) >> 5), tyhi = min(15, (gy+4) >> 5);
            int txlo = max(0, (gx-4) >> 5), txhi = min(15, (gx+4) >> 5);
            for (int ty = tylo; ty <= tyhi; ty++)
                for (int tx = txlo; tx <= txhi; tx++)
                    tileflag[(b*16 + ty)*16 + tx] = 1;  // idempotent store
        }
    }
}

// ---- wave-private helpers for k_entropy ----
// stage 16x40 bin-map rows (top row = gy0w) into this wave's LDS slice
__device__ __forceinline__ void stage_wave(const unsigned char* __restrict__ ib,
                                           unsigned* __restrict__ sw,
                                           int gy0w, int x0, int lane, bool interior) {
    if (interior) {
        const unsigned char* src = ib + (size_t)gy0w*WW + (x0-4);   // 4-aligned
#pragma unroll
        for (int k = 0; k < 3; k++) {
            int i = lane + 64*k;
            if (i < 160) {
                int r = i / 10, c = i - r*10;
                sw[r*10 + c] = *(const unsigned*)(src + (size_t)r*WW + c*4);
            }
        }
    } else {
        unsigned char* sb = (unsigned char*)sw;
#pragma unroll
        for (int k = 0; k < 10; k++) {
            int i = lane + 64*k;
            int r = i / 40, c = i - r*40;
            int gy = gy0w + r, gx = x0 + c - 4;
            unsigned char v = 255;
            if (gy >= 0 && gy < HH && gx >= 0 && gx < WW) v = ib[gy*WW + gx];
            sb[r*40 + c] = v;
        }
    }
}

// build this wave's 8x40 packed column hists (32 bins x 4-bit) from its sidx slice
__device__ __forceinline__ void build_wave(const unsigned char* __restrict__ sb,
                                           uint4* __restrict__ scw, int lane) {
#pragma unroll
    for (int k = 0; k < 5; k++) {
        int e = lane + 64*k;            // 320 entries
        int y = e / 40, c = e - y*40;
        unsigned w0=0,w1=0,w2=0,w3=0;
#pragma unroll
        for (int dy = 0; dy < 9; dy++) {
            unsigned bin = sb[(y + dy)*40 + c];
            unsigned inc = 1u << ((bin & 7u) * 4u);
            unsigned sel = bin >> 3;            // >=4 for OOB sentinel
            w0 += (sel == 0u) ? inc : 0u;
            w1 += (sel == 1u) ? inc : 0u;
            w2 += (sel == 2u) ? inc : 0u;
            w3 += (sel == 3u) ? inc : 0u;
        }
        scw[y*40 + c] = make_uint4(w0, w1, w2, w3);
    }
}

#define MLO 0x0F0F0F0Fu
#define ACCQ(Q) { a0 += (Q).x & MLO; a1 += ((Q).x >> 4) & MLO; \
                  a2 += (Q).y & MLO; a3 += ((Q).y >> 4) & MLO; \
                  a4 += (Q).z & MLO; a5 += ((Q).z >> 4) & MLO; \
                  a6 += (Q).w & MLO; a7 += ((Q).w >> 4) & MLO; }

__device__ __forceinline__ float ent_eval(const uint4* __restrict__ scw, int y, int xq,
                                          float l2t, float tot, const float* __restrict__ ftab) {
    const uint4* row = scw + y*40 + xq;
    uint4 q0 = row[0], q1 = row[1], q2 = row[2], q3 = row[3], q4 = row[4],
          q5 = row[5], q6 = row[6], q7 = row[7], q8 = row[8];
    unsigned a0=0,a1=0,a2=0,a3=0,a4=0,a5=0,a6=0,a7=0;
    ACCQ(q0) ACCQ(q1) ACCQ(q2) ACCQ(q3) ACCQ(q4) ACCQ(q5) ACCQ(q6) ACCQ(q7) ACCQ(q8)
    float S = 0.f;
    unsigned acc[8] = {a0,a1,a2,a3,a4,a5,a6,a7};
#pragma unroll
    for (int k = 0; k < 8; k++) {
        unsigned a = acc[k];
        S += ftab[a & 255u] + ftab[(a >> 8) & 255u]
           + ftab[(a >> 16) & 255u] + ftab[a >> 24];
    }
    return l2t - S / tot;
}

// barrier-free wave-private dual-chain 9x9/32-bin entropy.
// Wave w owns rows 8w..8w+7 of the tile; stages/builds/evals independently.
__global__ __launch_bounds__(256, 7) void k_entropy(const unsigned char* __restrict__ bidx1,
                                                    const unsigned char* __restrict__ bidx2,
                                                    const unsigned char* __restrict__ tileflag,
                                                    float* entbase,
                                                    unsigned* __restrict__ mm) {
    __shared__ unsigned sidxw[4][160];      // 2560 B: per-wave 16x40 staged bytes
    __shared__ uint4 scol[4][8*40];         // 20480 B: per-wave 8x40 packed col hists
    __shared__ float ftab[82];              // 328 B: n*log2(n), n<=81

    int b  = blockIdx.z;
    int y0 = blockIdx.y * TILE, x0 = blockIdx.x * TILE;
    int t  = threadIdx.x;
    int w  = t >> 6, lane = t & 63;
    bool interior = (blockIdx.x >= 1 && blockIdx.x <= 14 && blockIdx.y >= 1 && blockIdx.y <= 14);
    bool differs = (tileflag[(b*16 + blockIdx.y)*16 + blockIdx.x] != 0);  // block-uniform

    if (t < 82) ftab[t] = (t == 0) ? 0.0f : (float)t * __log2f((float)t);
    __syncthreads();   // the only block barrier

    const unsigned char* ib1 = bidx1 + (size_t)b * HWSZ;
    const unsigned char* ib2 = bidx2 + (size_t)b * HWSZ;
    unsigned* sw = sidxw[w];
    const unsigned char* sb = (const unsigned char*)sw;
    uint4* scw = scol[w];
    int gy0w = y0 + 8*w - 4;                // top staged row for this wave

    stage_wave(ib2, sw, gy0w, x0, lane, interior);
    __builtin_amdgcn_wave_barrier();
    build_wave(sb, scw, lane);
    __builtin_amdgcn_wave_barrier();

    float ev[4], totv[4], l2tv[4];
    int yl = lane >> 5, xq = lane & 31;
#pragma unroll
    for (int pp = 0; pp < 4; pp++) {
        int yloc = yl + 2*pp;
        int gy = y0 + 8*w + yloc, gx = x0 + xq;
        int rin = min(gy + 4, HH - 1) - max(gy - 4, 0) + 1;
        int cin = min(gx + 4, WW - 1) - max(gx - 4, 0) + 1;
        totv[pp] = (float)(rin * cin);
        l2tv[pp] = __log2f(totv[pp]);
        ev[pp] = ent_eval(scw, yloc, xq, l2tv[pp], totv[pp], ftab);   // e2 (base)
    }

    if (differs) {   // rare: re-stage map1, rebuild own scol, blend
        __builtin_amdgcn_wave_barrier();
        stage_wave(ib1, sw, gy0w, x0, lane, interior);
        __builtin_amdgcn_wave_barrier();
        build_wave(sb, scw, lane);
        __builtin_amdgcn_wave_barrier();
#pragma unroll
        for (int pp = 0; pp < 4; pp++) {
            int yloc = yl + 2*pp;
            float e1 = ent_eval(scw, yloc, xq, l2tv[pp], totv[pp], ftab);
            ev[pp] = ev[pp] + WBLEND * (e1 - ev[pp]);   // e2 + W*(e1-e2)
        }
    }

    float lmn = INFINITY, lmx = -INFINITY;
    float* eb = entbase + ((size_t)(b*NCH + 10)) * HWSZ;
#pragma unroll
    for (int pp = 0; pp < 4; pp++) {
        int yloc = yl + 2*pp;
        int gy = y0 + 8*w + yloc, gx = x0 + xq;
        eb[gy*WW + gx] = ev[pp];
        lmn = fminf(lmn, ev[pp]); lmx = fmaxf(lmx, ev[pp]);
    }
#pragma unroll
    for (int off = 32; off; off >>= 1) {
        lmn = fminf(lmn, __shfl_xor(lmn, off));
        lmx = fmaxf(lmx, __shfl_xor(lmx, off));
    }
    if (lane == 0) {
        atomicMin(&mm[(b*NCH + 10)*2    ], encf(lmn));
        atomicMax(&mm[(b*NCH + 10)*2 + 1], encf(lmx));
    }
}

// final: recompute diffs (float4), read raw entropy in-place, normalize 11 channels
__global__ __launch_bounds__(256) void k_final(const float4* __restrict__ x4,
                                               const unsigned* __restrict__ mm,
                                               float4* out4) {
    int b = blockIdx.y;
    const float4* xb = x4 + (size_t)b * 5 * (HWSZ/4);
    float4* ob = out4 + (size_t)b * NCH * (HWSZ/4);
    float mnv[11], dnv[11];
#pragma unroll
    for (int c = 0; c < 11; c++) {
        mnv[c] = decf(mm[(b*NCH + c)*2]);
        dnv[c] = decf(mm[(b*NCH + c)*2 + 1]) - mnv[c] + 1e-6f;
    }
    int p = blockIdx.x * blockDim.x + threadIdx.x;   // exact grid: 1 float4/thread
    float4 v0 = xb[p];
    float4 v1 = xb[(HWSZ/4) + p];
    float4 v2 = xb[2*(HWSZ/4) + p];
    float4 v3 = xb[3*(HWSZ/4) + p];
    float4 v4 = xb[4*(HWSZ/4) + p];
    float4 ve = ob[(size_t)10*(HWSZ/4) + p];   // raw entropy from k_entropy
    const float* a0 = &v0.x; const float* a1 = &v1.x; const float* a2 = &v2.x;
    const float* a3 = &v3.x; const float* a4 = &v4.x; const float* ae = &ve.x;
    float4 r[11];
    float* rr = &r[0].x;
#pragma unroll
    for (int c = 0; c < 4; c++) {
        float x0 = a0[c], x1 = a1[c], x2 = a2[c], x3 = a3[c], x4v = a4[c];
        float d[11] = { x0-x1, x0-x2, x0-x3, x0-x4v, x1-x2, x1-x3, x1-x4v,
                        x2-x3, x2-x4v, x3-x4v, ae[c] };
#pragma unroll
        for (int ch = 0; ch < 11; ch++) {
            rr[ch*4 + c] = (d[ch] - mnv[ch]) / dnv[ch];
        }
    }
#pragma unroll
    for (int ch = 0; ch < 11; ch++) {
        ob[(size_t)ch*(HWSZ/4) + p] = r[ch];
    }
}

extern "C" void kernel_launch(void* const* d_in, const int* in_sizes, int n_in,
                              void* d_out, int out_size, void* d_ws, size_t ws_size,
                              hipStream_t stream) {
    const float4* x4 = (const float4*)d_in[0];
    float4* out4 = (float4*)d_out;
    float* out = (float*)d_out;
    unsigned* mm = (unsigned*)d_ws;                            // 704 B
    unsigned char* tileflag = (unsigned char*)d_ws + 704;      // 2048 B
    // two bin-index maps (2 MB each) overlaid on d_out start (b0 ch0..ch3),
    // consumed by k_entropy before k_final overwrites them.
    unsigned char* bidx1 = (unsigned char*)d_out;
    unsigned char* bidx2 = (unsigned char*)d_out + (size_t)BATCH * HWSZ;

    k_init<<<1, 256, 0, stream>>>(mm, (unsigned long long*)tileflag);
    k_minmax<<<dim3(HWSZ/4/256, BATCH), 256, 0, stream>>>(x4, mm);
    k_binidx<<<dim3(HWSZ/4/256, BATCH), 256, 0, stream>>>(x4, mm, (uchar4*)bidx1, (uchar4*)bidx2, tileflag);
    k_entropy<<<dim3(WW/TILE, HH/TILE, BATCH), 256, 0, stream>>>(bidx1, bidx2, tileflag, out, mm);
    k_final<<<dim3(HWSZ/4/256, BATCH), 256, 0, stream>>>(x4, mm, out4);
}